// Round 1
// baseline (20.703 us; speedup 1.0000x reference)
//
#include <hip/hip_runtime.h>
#include <math.h>

#define SIGMA 0.2f
#define LOG2E 1.4426950408889634f

// One wave (64 lanes) per output row i: lane = kernel index m (0..63).
// 4 waves per 256-thread block; grid-stride loop over rows.
// Kernel points (64 m * 4 l) computed once per block into LDS, then held
// in registers pre-scaled by log2e/sigma^2.
__global__ __launch_bounds__(256) void corr_kernel(
    const float* __restrict__ normal,
    const int*   __restrict__ neighbour,
    const float* __restrict__ theta,
    const float* __restrict__ phi,
    float*       __restrict__ out,
    int n)
{
    __shared__ float kx[256], ky[256], kz[256];
    const int t = threadIdx.x;

    // Each of the 256 threads computes one kernel point (m = t>>2, l = t&3).
    {
        float th = theta[t];
        float ph = phi[t];
        float st = sinf(th), ct = cosf(th);
        float sp = sinf(ph), cp = cosf(ph);
        kx[t] = st * sp;   // sin(theta)*sin(phi)
        ky[t] = st * cp;   // sin(theta)*cos(phi)
        kz[t] = ct;        // cos(theta)
    }
    __syncthreads();

    const int m = t & 63;   // kernel index (lane within wave)
    const int w = t >> 6;   // wave id within block -> row sub-offset

    // Pre-scale kernel coords: arg2 = log2e * [ (p.k)/sigma^2 - (|p|^2+1)/(2 sigma^2) ]
    const float s = LOG2E / (SIGMA * SIGMA);
    float kxs[4], kys[4], kzs[4];
#pragma unroll
    for (int l = 0; l < 4; ++l) {
        kxs[l] = kx[m * 4 + l] * s;
        kys[l] = ky[m * 4 + l] * s;
        kzs[l] = kz[m * 4 + l] * s;
    }
    const float c1 = -LOG2E / (2.0f * SIGMA * SIGMA); // multiplies (|p|^2 + 1)

    for (int i = blockIdx.x * 4 + w; i < n; i += gridDim.x * 4) {
        // 4 point ids: self + 3 neighbours (wave-uniform loads, broadcast)
        int ids[4];
        ids[0] = i;
        ids[1] = neighbour[i * 3 + 0];
        ids[2] = neighbour[i * 3 + 1];
        ids[3] = neighbour[i * 3 + 2];

        float acc = 0.0f;
#pragma unroll
        for (int p = 0; p < 4; ++p) {
            const float px = normal[ids[p] * 3 + 0];
            const float py = normal[ids[p] * 3 + 1];
            const float pz = normal[ids[p] * 3 + 2];
            const float c2 = (px * px + py * py + pz * pz + 1.0f) * c1;
#pragma unroll
            for (int l = 0; l < 4; ++l) {
                float arg = fmaf(px, kxs[l], fmaf(py, kys[l], fmaf(pz, kzs[l], c2)));
                acc += __builtin_amdgcn_exp2f(arg);
            }
        }
        // lanes write consecutive m -> coalesced 256B store per wave
        out[(long long)i * 64 + m] = acc * (1.0f / 16.0f);
    }
}

extern "C" void kernel_launch(void* const* d_in, const int* in_sizes, int n_in,
                              void* d_out, int out_size, void* d_ws, size_t ws_size,
                              hipStream_t stream) {
    const float* normal    = (const float*)d_in[0];
    const int*   neighbour = (const int*)d_in[1];
    const float* theta     = (const float*)d_in[2];
    const float* phi       = (const float*)d_in[3];
    float*       out       = (float*)d_out;

    const int n = in_sizes[0] / 3;   // 50000

    int blocks = 1024;
    const int max_blocks = (n + 3) / 4;
    if (blocks > max_blocks) blocks = max_blocks;

    hipLaunchKernelGGL(corr_kernel, dim3(blocks), dim3(256), 0, stream,
                       normal, neighbour, theta, phi, out, n);
}